// Round 4
// baseline (147.755 us; speedup 1.0000x reference)
//
#include <hip/hip_runtime.h>
#include <hip/hip_bf16.h>

// Problem constants (from reference)
#define N_PARENT 16384
#define N_CHILD (8 * N_PARENT)   // 131072
#define CC 128                   // channels
#define KK 27                    // stencil taps

// GEMM tiling: 256x128 block tile, 8 waves (4Mx2N, 64x64 per wave), BK=64
#define BM 256
#define BN 128
#define BK 64
#define NSTAGE (KK * 2)          // 54 K-tiles
#define NBUF 3                   // triple buffer -> counted vmcnt never drains

// ws layout (bf16 element offsets)
#define XB_OFF 0
#define XB_ELEMS (N_PARENT * CC)             // 2,097,152
#define WT_OFF XB_ELEMS
#define WT_ELEMS (KK * CC * CC)              // 442,368
#define ZR_OFF (WT_OFF + WT_ELEMS)
#define ZR_ELEMS 128

typedef __attribute__((ext_vector_type(8))) __bf16 bf16x8;
typedef __attribute__((ext_vector_type(4))) float f32x4;

__device__ __forceinline__ void gll16(const void* g, void* l) {
  __builtin_amdgcn_global_load_lds(
      (const __attribute__((address_space(1))) unsigned int*)g,
      (__attribute__((address_space(3))) unsigned int*)l,
      16, 0, 0);
}

// Cast x to bf16, build w^T[k][d][c] in bf16, zero row.
__global__ void prep_kernel(const float* __restrict__ x,
                            const float* __restrict__ w,
                            __hip_bfloat16* __restrict__ ws) {
  const int stride = gridDim.x * blockDim.x;
  const int tid = blockIdx.x * blockDim.x + threadIdx.x;
  for (int i = tid; i < XB_ELEMS; i += stride)
    ws[XB_OFF + i] = __float2bfloat16(x[i]);
  for (int j = tid; j < WT_ELEMS; j += stride) {
    const int k = j / (CC * CC);
    const int rem = j - k * CC * CC;
    const int d = rem >> 7;   // output channel
    const int c = rem & 127;  // input channel
    ws[WT_OFF + j] = __float2bfloat16(w[k * CC * CC + c * CC + d]);
  }
  if (tid < ZR_ELEMS) ws[ZR_OFF + tid] = __float2bfloat16(0.0f);
}

// 8-phase-style schedule (m201 template, 4 phases per K-tile):
//   ph: { frag ds_reads ; stage gll16s for tile t+2 ; barrier ;
//         lgkmcnt(0) ; setprio(1) ; 8 MFMA ; setprio(0) ; barrier }
// vmcnt(6) once per tile (ph3): waits tile t+1's 6 loads, leaves tile t+2's
// 6 in flight across the barrier. LDS swizzle: phys_col = log_col ^ (row&7)*8,
// applied as inverse on the global source (gll16 dest stays linear).
__global__ __launch_bounds__(512, 2) void upconv_kernel(
    const int* __restrict__ neigh,
    const __hip_bfloat16* __restrict__ ws,
    const float* __restrict__ bias,
    float* __restrict__ out) {
  __shared__ __align__(16) __hip_bfloat16 As[NBUF][BM * BK];  // 96 KB
  __shared__ __align__(16) __hip_bfloat16 Bs[NBUF][BN * BK];  // 48 KB
  __shared__ short ridx[BM * KK];                             // 13.5 KB

  const __hip_bfloat16* xb = ws + XB_OFF;
  const __hip_bfloat16* wT = ws + WT_OFF;
  const __hip_bfloat16* zr = ws + ZR_OFF;

  const int tid = threadIdx.x;
  const int wv = tid >> 6;   // wave 0..7
  const int l = tid & 63;    // lane
  const int wr = wv >> 1;    // wave row 0..3 (64-row strip)
  const int wc = wv & 1;     // wave col 0..1 (64-col strip)
  const int row0 = blockIdx.x * BM;

  // Preload neighbor indices (coalesced), pre-shifted to parent rows.
  for (int j = tid; j < BM * KK; j += 512) {
    const int nv = neigh[row0 * KK + j];
    ridx[j] = (short)((nv >= 0) ? (nv >> 3) : -1);
  }
  __syncthreads();

  const int lr = l & 15;          // frag row within 16
  const int lk = (l >> 4) * 8;    // frag k-chunk offset (elements)
  const int lrow = l >> 3;        // staging: row within 8-row group
  const int scol = ((l & 7) ^ lrow) * 8;  // pre-swizzled global src col
  const int sw = (lr & 7) * 8;            // frag-read swizzle term

  f32x4 acc[4][4] = {};
  bf16x8 a[4], b[2];

  // --- staging: each wave writes its own 8-row slice of a 64-row round ----
  auto stageA = [&](int bf, int h, int r, int rid) {
    const __hip_bfloat16* ga =
        (rid >= 0) ? (xb + (size_t)rid * CC + h + scol) : (zr + scol);
    gll16(ga, &As[bf][(r * 64 + wv * 8) * BK]);
  };
  auto stageB = [&](int bf, int k, int h, int r) {
    const int d = r * 64 + wv * 8 + lrow;
    gll16(wT + (size_t)k * (CC * CC) + (size_t)d * CC + h + scol,
          &Bs[bf][(r * 64 + wv * 8) * BK]);
  };

  // --- fragment reads (swizzled) ------------------------------------------
  auto readA = [&](int bf, int kc) {
#pragma unroll
    for (int m = 0; m < 4; ++m)
      a[m] = *reinterpret_cast<const bf16x8*>(
          &As[bf][(wr * 64 + m * 16 + lr) * BK + ((kc * 32 + lk) ^ sw)]);
  };
  auto readB = [&](int bf, int kc, int nh) {
#pragma unroll
    for (int i = 0; i < 2; ++i)
      b[i] = *reinterpret_cast<const bf16x8*>(
          &Bs[bf][(wc * 64 + (nh * 2 + i) * 16 + lr) * BK +
                  ((kc * 32 + lk) ^ sw)]);
  };
  auto mmac = [&](int nh) {
#pragma unroll
    for (int m = 0; m < 4; ++m)
#pragma unroll
      for (int i = 0; i < 2; ++i)
        acc[m][nh * 2 + i] = __builtin_amdgcn_mfma_f32_16x16x32_bf16(
            a[m], b[i], acc[m][nh * 2 + i], 0, 0, 0);
  };

  // --- prologue: stage tiles 0 (buf0) and 1 (buf1), 12 loads/wave ---------
  {
    int rid0[4];
#pragma unroll
    for (int r = 0; r < 4; ++r)
      rid0[r] = ridx[(r * 64 + wv * 8 + lrow) * KK + 0];
    stageB(0, 0, 0, 0);  stageB(0, 0, 0, 1);
    stageA(0, 0, 0, rid0[0]);  stageA(0, 0, 1, rid0[1]);
    stageA(0, 0, 2, rid0[2]);  stageA(0, 0, 3, rid0[3]);
    stageB(1, 0, 64, 0); stageB(1, 0, 64, 1);
    stageA(1, 64, 0, rid0[0]); stageA(1, 64, 1, rid0[1]);
    stageA(1, 64, 2, rid0[2]); stageA(1, 64, 3, rid0[3]);
  }
  asm volatile("s_waitcnt vmcnt(6)" ::: "memory");  // tile0 landed
  __syncthreads();

  // --- main loop: 54 K-tiles x 4 phases -----------------------------------
  for (int s = 0; s < NSTAGE; ++s) {
    const int bf = s % 3;            // buffer being computed
    const int sb = (s + 2) % 3;      // buffer being staged (tile s+2)
    const int k2 = (s + 2) >> 1;     // staged tile's stencil tap
    const int h2 = (s & 1) << 6;     // staged tile's c-half (same parity)
    const bool st = (s + 2) < NSTAGE;

    int ridv[4] = {-1, -1, -1, -1};

    // ph0: frags(kc0: A all, B n01) | stage B r0,r1 | ridx prefetch
    readA(bf, 0);
    readB(bf, 0, 0);
    if (st) {
#pragma unroll
      for (int r = 0; r < 4; ++r)
        ridv[r] = ridx[(r * 64 + wv * 8 + lrow) * KK + k2];
      stageB(sb, k2, h2, 0);
      stageB(sb, k2, h2, 1);
    }
    __builtin_amdgcn_s_barrier();
    asm volatile("s_waitcnt lgkmcnt(0)" ::: "memory");
    __builtin_amdgcn_s_setprio(1);
    mmac(0);
    __builtin_amdgcn_s_setprio(0);
    __builtin_amdgcn_s_barrier();

    // ph1: frags(kc0: B n23) | stage A r0,r1
    readB(bf, 0, 1);
    if (st) { stageA(sb, h2, 0, ridv[0]); stageA(sb, h2, 1, ridv[1]); }
    __builtin_amdgcn_s_barrier();
    asm volatile("s_waitcnt lgkmcnt(0)" ::: "memory");
    __builtin_amdgcn_s_setprio(1);
    mmac(1);
    __builtin_amdgcn_s_setprio(0);
    __builtin_amdgcn_s_barrier();

    // ph2: frags(kc1: A all, B n01) | stage A r2,r3
    readA(bf, 1);
    readB(bf, 1, 0);
    if (st) { stageA(sb, h2, 2, ridv[2]); stageA(sb, h2, 3, ridv[3]); }
    __builtin_amdgcn_s_barrier();
    asm volatile("s_waitcnt lgkmcnt(0)" ::: "memory");
    __builtin_amdgcn_s_setprio(1);
    mmac(0);
    __builtin_amdgcn_s_setprio(0);
    __builtin_amdgcn_s_barrier();

    // ph3: frags(kc1: B n23) | counted vmcnt at tile boundary
    readB(bf, 1, 1);
    __builtin_amdgcn_s_barrier();
    asm volatile("s_waitcnt lgkmcnt(0)" ::: "memory");
    __builtin_amdgcn_s_setprio(1);
    mmac(1);
    __builtin_amdgcn_s_setprio(0);
    if (s < NSTAGE - 2)
      asm volatile("s_waitcnt vmcnt(6)" ::: "memory");  // tile s+1 landed
    else
      asm volatile("s_waitcnt vmcnt(0)" ::: "memory");  // final drain
    __builtin_amdgcn_s_barrier();
  }

  // --- epilogue: C/D layout col=lane&15, row=(lane>>4)*4+q ---------------
  float bv[4];
#pragma unroll
  for (int n = 0; n < 4; ++n) bv[n] = bias[wc * 64 + n * 16 + lr];
  const int rbase = row0 + wr * 64 + (l >> 4) * 4;
#pragma unroll
  for (int m = 0; m < 4; ++m)
#pragma unroll
    for (int n = 0; n < 4; ++n)
#pragma unroll
      for (int q = 0; q < 4; ++q)
        out[(size_t)(rbase + m * 16 + q) * CC + wc * 64 + n * 16 + lr] =
            acc[m][n][q] + bv[n];
}

extern "C" void kernel_launch(void* const* d_in, const int* in_sizes, int n_in,
                              void* d_out, int out_size, void* d_ws,
                              size_t ws_size, hipStream_t stream) {
  const float* x = (const float*)d_in[0];
  const float* w = (const float*)d_in[1];
  const float* b = (const float*)d_in[2];
  const int* neigh = (const int*)d_in[3];
  __hip_bfloat16* ws = (__hip_bfloat16*)d_ws;
  float* out = (float*)d_out;

  hipLaunchKernelGGL(prep_kernel, dim3(512), dim3(256), 0, stream, x, w, ws);
  hipLaunchKernelGGL(upconv_kernel, dim3(N_CHILD / BM), dim3(512), 0, stream,
                     neigh, ws, b, out);
}